// Round 4
// baseline (7465.701 us; speedup 1.0000x reference)
//
#include <hip/hip_runtime.h>
#include <hip/hip_bf16.h>
#include <math.h>

// ---------------- problem constants ----------------
#define NGRP 16     // batch groups (one per batch element)
#define GWG  16     // workgroups per group: 8 attn (one/head) + 8 ff
#define NATT 8
#define NBLK (NGRP*GWG)   // 256 = CU count -> all co-resident, 1 WG/CU
#define NTHR 512
#define TSEQ 48
#define DDIM 256
#define HDIM 32
#define NLAY 3
#define NOUT 6

// ---------------- ws layout ----------------
#define CNT_OFF   0u
#define CNT_BYTES 4096u          // 16 counters, 256B apart
#define GRP_OFF   4096u
#define GRP_STRF  5120u          // floats per group block
#define XG_F   0                 // [256]  shared x at l==0
#define PO_F   256               // [8*256] oproj partials
#define PF_F   2304              // [8*256] ff2 partials
#define CAL_F  4352              // [3*256] cross-attn constants

__device__ __forceinline__ unsigned short f2bf(float f) {
  __hip_bfloat16 h = __float2bfloat16(f);
  union { __hip_bfloat16 h; unsigned short u; } c; c.h = h; return c.u;
}
__device__ __forceinline__ unsigned int pk(float a, float b) {
  return (unsigned int)f2bf(a) | ((unsigned int)f2bf(b) << 16);
}
__device__ __forceinline__ void bfp(unsigned int u, float& lo, float& hi) {
  union { unsigned int i; float f; } a, b;
  a.i = u << 16; b.i = u & 0xffff0000u; lo = a.f; hi = b.f;
}
__device__ __forceinline__ float gelu_exact(float x) {
  return 0.5f * x * (1.0f + erff(x * 0.70710678118654752f));
}

// ---------------- one-shot per-(g,l) constants: memvec chain + cross-attn const ----
// cross-attn K/V rows identical over T -> softmax uniform -> out = V(memvec): a constant.
__global__ void precompute_ca(const float* zs, const float* zk,
                              const float* mw1, const float* mb1,
                              const float* mlg, const float* mlb,
                              const float* mw2, const float* mb2,
                              const float* cqw, const float* cqb,
                              const float* cow, const float* cob,
                              unsigned char* ws) {
  const int g = blockIdx.x & 15, l = blockIdx.x >> 4;
  const int tid = threadIdx.x;           // 256 threads
  __shared__ float cond[128], h[256], mvv[256], vv[256], lred[16];

  auto lnstat = [&](float v, float& m, float& rs) {
    float a = v, b = v * v;
    #pragma unroll
    for (int off = 32; off; off >>= 1) { a += __shfl_xor(a, off); b += __shfl_xor(b, off); }
    if ((tid & 63) == 0) { lred[tid >> 6] = a; lred[4 + (tid >> 6)] = b; }
    __syncthreads();
    float sa = lred[0]+lred[1]+lred[2]+lred[3];
    float sb = lred[4]+lred[5]+lred[6]+lred[7];
    m = sa * (1.0f/256.0f);
    rs = rsqrtf(sb * (1.0f/256.0f) - m*m + 1e-5f);
    __syncthreads();
  };

  if (tid < 128) cond[tid] = (tid < 64) ? zs[g*64 + tid] : zk[g*64 + tid - 64];
  __syncthreads();
  float acc = mb1[tid];
  { const float* w = mw1 + (size_t)tid * 128;
    for (int k = 0; k < 128; k += 4) {
      float4 q = *(const float4*)(w + k);
      acc += q.x*cond[k] + q.y*cond[k+1] + q.z*cond[k+2] + q.w*cond[k+3];
    } }
  float m, rs; lnstat(acc, m, rs);
  h[tid] = gelu_exact((acc - m) * rs * mlg[tid] + mlb[tid]);
  __syncthreads();
  float a2 = mb2[tid];
  { const float* w = mw2 + (size_t)tid * 256;
    for (int k = 0; k < 256; k += 4) {
      float4 q = *(const float4*)(w + k);
      a2 += q.x*h[k] + q.y*h[k+1] + q.z*h[k+2] + q.w*h[k+3];
    } }
  mvv[tid] = a2;
  __syncthreads();
  float a3 = cqb[l*768 + 512 + tid];
  { const float* w = cqw + ((size_t)l*768 + 512 + tid) * 256;
    for (int k = 0; k < 256; k += 4) {
      float4 q = *(const float4*)(w + k);
      a3 += q.x*mvv[k] + q.y*mvv[k+1] + q.z*mvv[k+2] + q.w*mvv[k+3];
    } }
  vv[tid] = a3;
  __syncthreads();
  float a4 = cob[l*256 + tid];
  { const float* w = cow + ((size_t)l*256 + tid) * 256;
    for (int k = 0; k < 256; k += 4) {
      float4 q = *(const float4*)(w + k);
      a4 += q.x*vv[k] + q.y*vv[k+1] + q.z*vv[k+2] + q.w*vv[k+3];
    } }
  ((float*)(ws + GRP_OFF))[(size_t)g * GRP_STRF + CAL_F + l*256 + tid] = a4;
}

struct DecP {
  const float *start_token, *emb_w, *emb_b;
  const float *sa_qkv_w, *sa_qkv_b, *sa_o_w, *sa_o_b;
  const float *ln1_g, *ln1_b, *ln2_g, *ln2_b, *ln3_g, *ln3_b;
  const float *ff1_w, *ff1_b, *ff2_w, *ff2_b;
  const float *op_w1, *op_b1, *op_w2, *op_b2;
  float* out;
  unsigned char* ws;
};

// Persistent decoder: 16 groups x 16 WGs (8 attn + 8 ff), weights register-resident.
// All 16 WGs of group g land on XCD g%8 under round-robin dispatch (perf-only assumption;
// correctness uses agent-scope fences).
__global__ __launch_bounds__(NTHR, 1) void decoder_persistent(DecP p) {
  const int blk = blockIdx.x;
  const int g = blk % NGRP;
  const int s = blk / NGRP;            // 0..15
  const bool isatt = (s < NATT);       // block-uniform
  const int s8 = s - NATT;
  const int tid = threadIdx.x;

  unsigned int* cnt = (unsigned int*)(p.ws + CNT_OFF) + (size_t)g * 64;
  float* grp = (float*)(p.ws + GRP_OFF) + (size_t)g * GRP_STRF;
  float* Xg = grp + XG_F;
  float* Po = grp + PO_F;
  float* Pf = grp + PF_F;
  const float* CALW = grp + CAL_F;

  __shared__ float xls[DDIM], x2ls[DDIM];
  __shared__ float red[NTHR];
  __shared__ float lred[16];
  __shared__ float qb[HDIM], ah[HDIM], sc[64], fxl[128];
  __shared__ float kc[NLAY*TSEQ*33], vc[NLAY*TSEQ*33];   // padded stride 33
  __shared__ float cals[768], obias[768], ff2b[768];
  __shared__ float ln1g[768], ln1b[768], ln2g[768], ln2b[768], ln3g[768], ln3b[768];
  __shared__ float qkvb[288], ff1b[384];
  __shared__ float embw[DDIM*NOUT], embb[DDIM];
  __shared__ float opb1[128], opw2[NOUT*128], opb2[8], stok[8], OUTV[8];

  // ---- register-resident bf16 weights (union across roles; static indexing only) ----
  // attn: W1[l] = QKV own head (thread (olin<96, kk)); W2[l][24..31] = Wo^T own head
  //        (thread (oB,khB)); W2[0][0..23]+W2[1][0..7] = op_w1 (thread (tid>>2, kk)).
  // ff:   W1[l] = ff1 own 128 rows; W2[l][0..31] = ff2 own 128 K-cols.
  unsigned int W1[3][32];
  unsigned int W2[3][32];

  const int olin = tid >> 2, kk = tid & 3;    // GEMV-A mapping (4 thr/output)
  const int oB = tid & 255, khB = tid >> 8;   // GEMV-B mapping (2 thr/output)

  // ---- small params -> LDS ----
  for (int i = tid; i < 768; i += NTHR) {
    cals[i]  = CALW[i];
    obias[i] = p.sa_o_b[i];
    ff2b[i]  = p.ff2_b[i];
    ln1g[i] = p.ln1_g[i]; ln1b[i] = p.ln1_b[i];
    ln2g[i] = p.ln2_g[i]; ln2b[i] = p.ln2_b[i];
    ln3g[i] = p.ln3_g[i]; ln3b[i] = p.ln3_b[i];
  }
  if (isatt) {
    for (int i = tid; i < 288; i += NTHR) {
      int l = i / 96, r = i % 96, sect = (r >> 5), o = r & 31;
      qkvb[i] = p.sa_qkv_b[l*768 + sect*256 + s*32 + o];
    }
    for (int i = tid; i < DDIM*NOUT; i += NTHR) embw[i] = p.emb_w[i];
    for (int i = tid; i < DDIM; i += NTHR) embb[i] = p.emb_b[i];
    for (int i = tid; i < 128; i += NTHR) opb1[i] = p.op_b1[i];
    for (int i = tid; i < NOUT*128; i += NTHR) opw2[i] = p.op_w2[i];
    if (tid < NOUT) { opb2[tid] = p.op_b2[tid]; stok[tid] = p.start_token[tid]; }
  } else {
    for (int i = tid; i < 384; i += NTHR) {
      int l = i >> 7, o = i & 127;
      ff1b[i] = p.ff1_b[l*1024 + s8*128 + o];
    }
  }

  // ---- weight registers (one-time; k-order i*32+kk*8+j for bank-free LDS reads) ----
  if (isatt) {
    if (olin < 96) {
      int sect = olin >> 5, o = olin & 31;
      #pragma unroll
      for (int l = 0; l < 3; ++l) {
        const float* w = p.sa_qkv_w + ((size_t)(l*768 + sect*256 + s*32 + o)) * 256;
        #pragma unroll
        for (int i = 0; i < 8; ++i)
          #pragma unroll
          for (int j2 = 0; j2 < 4; ++j2) {
            int k = i*32 + kk*8 + j2*2;
            W1[l][i*4 + j2] = pk(w[k], w[k+1]);
          }
      }
    }
    #pragma unroll
    for (int l = 0; l < 3; ++l) {
      const float* w = p.sa_o_w + ((size_t)(l*256 + oB)) * 256 + s*32 + khB*16;
      #pragma unroll
      for (int j2 = 0; j2 < 8; ++j2) W2[l][24 + j2] = pk(w[2*j2], w[2*j2+1]);
    }
    {
      const float* w = p.op_w1 + (size_t)(tid >> 2) * 256;   // o1 = tid>>2 in [0,128)
      #pragma unroll
      for (int i = 0; i < 8; ++i)
        #pragma unroll
        for (int j2 = 0; j2 < 4; ++j2) {
          int c = i*4 + j2, k = i*32 + kk*8 + j2*2;
          unsigned int v = pk(w[k], w[k+1]);
          if (c < 24) W2[0][c] = v; else W2[1][c - 24] = v;
        }
    }
  } else {
    #pragma unroll
    for (int l = 0; l < 3; ++l) {
      const float* w1p = p.ff1_w + ((size_t)(l*1024 + s8*128 + olin)) * 256;
      #pragma unroll
      for (int i = 0; i < 8; ++i)
        #pragma unroll
        for (int j2 = 0; j2 < 4; ++j2) {
          int k = i*32 + kk*8 + j2*2;
          W1[l][i*4 + j2] = pk(w1p[k], w1p[k+1]);
        }
      const float* w2p = p.ff2_w + ((size_t)(l*256 + oB)) * 1024 + s8*128;
      #pragma unroll
      for (int i = 0; i < 8; ++i)
        #pragma unroll
        for (int j2 = 0; j2 < 4; ++j2) {
          int kl = i*16 + khB*8 + j2*2;
          W2[l][i*4 + j2] = pk(w2p[kl], w2p[kl+1]);
        }
    }
  }

  // ---- group barrier (proven R1/R3): agent release/acquire; cheap now that
  // the L2 working set is ~nothing (weights live in registers/LDS).
  unsigned int barcount = 0;
  auto group_barrier = [&]() {
    __syncthreads();
    ++barcount;
    if (tid == 0) {
      __threadfence();
      __hip_atomic_fetch_add(cnt, 1u, __ATOMIC_RELEASE, __HIP_MEMORY_SCOPE_AGENT);
      unsigned int target = (unsigned int)GWG * barcount;
      while (__hip_atomic_load(cnt, __ATOMIC_RELAXED, __HIP_MEMORY_SCOPE_AGENT) < target)
        __builtin_amdgcn_s_sleep(1);
      (void)__hip_atomic_load(cnt, __ATOMIC_ACQUIRE, __HIP_MEMORY_SCOPE_AGENT);
    }
    __syncthreads();
  };

  auto lnstats = [&](float v, float& m, float& rs) {
    float a = v, b = v * v;
    #pragma unroll
    for (int off = 32; off; off >>= 1) { a += __shfl_xor(a, off); b += __shfl_xor(b, off); }
    if ((tid & 63) == 0) { lred[tid >> 6] = a; lred[8 + (tid >> 6)] = b; }
    __syncthreads();
    float sa = lred[0]+lred[1]+lred[2]+lred[3]+lred[4]+lred[5]+lred[6]+lred[7];
    float sb = lred[8]+lred[9]+lred[10]+lred[11]+lred[12]+lred[13]+lred[14]+lred[15];
    m = sa * (1.0f/256.0f);
    rs = rsqrtf(sb * (1.0f/256.0f) - m*m + 1e-5f);
    __syncthreads();
  };

  const float divv = (tid < 256) ? expf(-0.035977892078031968f * (float)(2*(tid>>1))) : 0.f;
  __syncthreads();

  for (int t = 0; t < TSEQ; ++t) {
    #pragma unroll
    for (int l = 0; l < NLAY; ++l) {
      // ================= PHASE A =================
      if (l == 0) {
        if (isatt) {
          if (tid < NOUT) sc[tid] = (t == 0) ? stok[tid] : OUTV[tid];
          __syncthreads();
          if (tid < 256) {
            float ang = (float)t * divv;
            float pe = (tid & 1) ? cosf(ang) : sinf(ang);
            float acc = embb[tid] + pe;
            #pragma unroll
            for (int j = 0; j < NOUT; ++j) acc += sc[j] * embw[tid*NOUT + j];
            xls[tid] = acc;
            if (s == 0) Xg[tid] = acc;     // posted for ff WGs (read after B1)
          }
          __syncthreads();
        }
      } else {
        float r2 = 0.f;
        if (tid < 256) {
          r2 = x2ls[tid] + ff2b[(l-1)*256 + tid];
          #pragma unroll
          for (int ss = 0; ss < 8; ++ss) r2 += Pf[ss*256 + tid];
        }
        float m, rs; lnstats(r2, m, rs);
        if (tid < 256)
          xls[tid] = (r2 - m) * rs * ln3g[(l-1)*256 + tid] + ln3b[(l-1)*256 + tid];
        __syncthreads();
      }
      if (isatt) {
        // qkv (own head) from registers
        if (olin < 96) {
          float acc = 0.f;
          #pragma unroll
          for (int i = 0; i < 8; ++i)
            #pragma unroll
            for (int j2 = 0; j2 < 4; ++j2) {
              int k = i*32 + kk*8 + j2*2;
              float lo, hi; bfp(W1[l][i*4 + j2], lo, hi);
              acc += xls[k]*lo + xls[k+1]*hi;
            }
          red[tid] = acc;
        }
        __syncthreads();
        if (tid < 96) {
          float v = red[tid*4] + red[tid*4+1] + red[tid*4+2] + red[tid*4+3] + qkvb[l*96 + tid];
          int sect = tid >> 5, o = tid & 31;
          if (sect == 0) qb[o] = v;
          else if (sect == 1) kc[(l*TSEQ + t)*33 + o] = v;
          else vc[(l*TSEQ + t)*33 + o] = v;
        }
        __syncthreads();
        // scores + softmax (wave 0)
        if (tid < 64) {
          float scj = -1e30f;
          if (tid <= t) {
            const float* kr = &kc[(l*TSEQ + tid)*33];
            float a = 0.f;
            #pragma unroll
            for (int d = 0; d < HDIM; ++d) a += qb[d] * kr[d];
            scj = a * 0.17677669529663687f;
          }
          float mx = scj;
          #pragma unroll
          for (int off = 32; off; off >>= 1) mx = fmaxf(mx, __shfl_xor(mx, off));
          float e = (tid <= t) ? expf(scj - mx) : 0.f;
          float su = e;
          #pragma unroll
          for (int off = 32; off; off >>= 1) su += __shfl_xor(su, off);
          sc[tid] = e / su;
        }
        __syncthreads();
        // PV: 256 threads (d = tid>>3, jg = tid&7) + 8-lane shuffle reduce
        if (tid < 256) {
          int d = tid >> 3, jg = tid & 7;
          float acc = 0.f;
          for (int j = jg; j <= t; j += 8) acc += sc[j] * vc[(l*TSEQ + j)*33 + d];
          acc += __shfl_xor(acc, 1);
          acc += __shfl_xor(acc, 2);
          acc += __shfl_xor(acc, 4);
          if (jg == 0) ah[d] = acc;
        }
        __syncthreads();
        // oproj partial (own head K-rows) from registers
        {
          float acc = 0.f;
          #pragma unroll
          for (int j2 = 0; j2 < 8; ++j2) {
            float lo, hi; bfp(W2[l][24 + j2], lo, hi);
            acc += ah[khB*16 + 2*j2]*lo + ah[khB*16 + 2*j2 + 1]*hi;
          }
          red[tid] = acc;
        }
        __syncthreads();
        if (tid < 256) Po[s*256 + tid] = red[tid] + red[tid + 256];
      }
      group_barrier();   // B1

      // ================= PHASE B =================
      if (!isatt && l == 0) {
        if (tid < 256) xls[tid] = Xg[tid];
        __syncthreads();
      }
      float r = 0.f;
      if (tid < 256) {
        r = xls[tid] + obias[l*256 + tid];
        #pragma unroll
        for (int ss = 0; ss < 8; ++ss) r += Po[ss*256 + tid];
      }
      float m1, rs1; lnstats(r, m1, rs1);
      float z = 0.f;
      if (tid < 256)
        z = (r - m1)*rs1*ln1g[l*256 + tid] + ln1b[l*256 + tid] + cals[l*256 + tid];
      float m2, rs2; lnstats(z, m2, rs2);
      if (tid < 256) x2ls[tid] = (z - m2)*rs2*ln2g[l*256 + tid] + ln2b[l*256 + tid];
      __syncthreads();
      if (!isatt) {
        // ff1 (own 128 rows)
        {
          float acc = 0.f;
          #pragma unroll
          for (int i = 0; i < 8; ++i)
            #pragma unroll
            for (int j2 = 0; j2 < 4; ++j2) {
              int k = i*32 + kk*8 + j2*2;
              float lo, hi; bfp(W1[l][i*4 + j2], lo, hi);
              acc += x2ls[k]*lo + x2ls[k+1]*hi;
            }
          red[tid] = acc;
        }
        __syncthreads();
        if (tid < 128)
          fxl[tid] = gelu_exact(red[tid*4] + red[tid*4+1] + red[tid*4+2] + red[tid*4+3]
                                + ff1b[l*128 + tid]);
        __syncthreads();
        // ff2 partial (own 128 K-cols)
        {
          float acc = 0.f;
          #pragma unroll
          for (int i = 0; i < 8; ++i)
            #pragma unroll
            for (int j2 = 0; j2 < 4; ++j2) {
              int kl = i*16 + khB*8 + j2*2;
              float lo, hi; bfp(W2[l][i*4 + j2], lo, hi);
              acc += fxl[kl]*lo + fxl[kl+1]*hi;
            }
          red[tid] = acc;
        }
        __syncthreads();
        if (tid < 256) Pf[s8*256 + tid] = red[tid] + red[tid + 256];
      }
      group_barrier();   // B2
    } // l

    // ================= PHASE O (attn WGs, redundant; no trailing barrier) =========
    if (isatt) {
      float r2 = 0.f;
      if (tid < 256) {
        r2 = x2ls[tid] + ff2b[2*256 + tid];
        #pragma unroll
        for (int ss = 0; ss < 8; ++ss) r2 += Pf[ss*256 + tid];
      }
      float m, rs; lnstats(r2, m, rs);
      if (tid < 256) xls[tid] = (r2 - m)*rs*ln3g[2*256 + tid] + ln3b[2*256 + tid];
      __syncthreads();
      // op1 GEMV from register union
      {
        float acc = 0.f;
        #pragma unroll
        for (int i = 0; i < 8; ++i)
          #pragma unroll
          for (int j2 = 0; j2 < 4; ++j2) {
            int c = i*4 + j2, k = i*32 + kk*8 + j2*2;
            unsigned int wv = (c < 24) ? W2[0][c] : W2[1][c - 24];
            float lo, hi; bfp(wv, lo, hi);
            acc += xls[k]*lo + xls[k+1]*hi;
          }
        red[tid] = acc;
      }
      __syncthreads();
      if (tid < 128)
        fxl[tid] = gelu_exact(red[tid*4] + red[tid*4+1] + red[tid*4+2] + red[tid*4+3]
                              + opb1[tid]);
      __syncthreads();
      if (tid < 192) {
        int oo = tid >> 5, kl = tid & 31;
        float acc = fxl[kl]*opw2[oo*128 + kl] + fxl[kl+32]*opw2[oo*128 + kl+32]
                  + fxl[kl+64]*opw2[oo*128 + kl+64] + fxl[kl+96]*opw2[oo*128 + kl+96];
        #pragma unroll
        for (int off = 16; off; off >>= 1) acc += __shfl_xor(acc, off);
        if (kl == 0) {
          float v = acc + opb2[oo];
          OUTV[oo] = v;
          if (s == 0) p.out[((size_t)g*TSEQ + t)*NOUT + oo] = v;
        }
      }
      __syncthreads();
    }
  } // t
}

extern "C" void kernel_launch(void* const* d_in, const int* in_sizes, int n_in,
                              void* d_out, int out_size, void* d_ws, size_t ws_size,
                              hipStream_t stream) {
  const float* const* F = (const float* const*)d_in;
  const float* z_style = F[0]; const float* z_skill = F[1];
  DecP p;
  p.start_token = F[2];
  const float* mem_w1 = F[3]; const float* mem_b1 = F[4];
  const float* mem_ln_g = F[5]; const float* mem_ln_b = F[6];
  const float* mem_w2 = F[7]; const float* mem_b2 = F[8];
  p.emb_w = F[9]; p.emb_b = F[10];
  p.sa_qkv_w = F[11]; p.sa_qkv_b = F[12];
  p.sa_o_w = F[13]; p.sa_o_b = F[14];
  const float* ca_qkv_w = F[15]; const float* ca_qkv_b = F[16];
  const float* ca_o_w = F[17]; const float* ca_o_b = F[18];
  p.ln1_g = F[19]; p.ln1_b = F[20]; p.ln2_g = F[21]; p.ln2_b = F[22];
  p.ln3_g = F[23]; p.ln3_b = F[24];
  p.ff1_w = F[25]; p.ff1_b = F[26];
  p.ff2_w = F[27]; p.ff2_b = F[28];
  p.op_w1 = F[29]; p.op_b1 = F[30]; p.op_w2 = F[31]; p.op_b2 = F[32];
  p.out = (float*)d_out;
  p.ws  = (unsigned char*)d_ws;

  hipMemsetAsync((char*)d_ws + CNT_OFF, 0, CNT_BYTES, stream);
  precompute_ca<<<dim3(48), dim3(256), 0, stream>>>(z_style, z_skill, mem_w1, mem_b1,
                                                    mem_ln_g, mem_ln_b, mem_w2, mem_b2,
                                                    ca_qkv_w, ca_qkv_b, ca_o_w, ca_o_b,
                                                    (unsigned char*)d_ws);
  decoder_persistent<<<dim3(NBLK), dim3(NTHR), 0, stream>>>(p);
}

// Round 5
// 3443.012 us; speedup vs baseline: 2.1684x; 2.1684x over previous
//
#include <hip/hip_runtime.h>
#include <hip/hip_bf16.h>
#include <math.h>

// ---------------- problem constants ----------------
#define NGRP 16     // batch groups (one per batch element)
#define GWG  8      // workgroups per group (= heads)
#define NBLK (NGRP*GWG)   // 128
#define NTHR 512
#define TSEQ 48
#define DDIM 256
#define HDIM 32
#define NLAY 3
#define NOUT 6

// ---------------- ws layout ----------------
#define CNT_OFF   0u
#define CNT_BYTES 4096u          // 16 counters, 256B apart
#define GRP_OFF   4096u
#define GRP_STRF  5120u          // floats per group block
#define PO_F   0                 // [8*256] oproj partials
#define PF_F   2048              // [8*256] ff2 partials
#define CAL_F  4096              // [3*256] cross-attn constants
#define WB_OFF 331776u           // bf16 weights (element offsets below)
#define WOFF_QKV 0u
#define WOFF_WO  589824u
#define WOFF_F1  786432u
#define WOFF_F2  1572864u
#define WOFF_OP1 2359296u
#define NCVT     2392064u

__device__ __forceinline__ void bfp(unsigned int u, float& lo, float& hi) {
  union { unsigned int i; float f; } a, b;
  a.i = u << 16; b.i = u & 0xffff0000u; lo = a.f; hi = b.f;
}
__device__ __forceinline__ float gelu_exact(float x) {
  return 0.5f * x * (1.0f + erff(x * 0.70710678118654752f));
}
// dot of one uint4 (8 packed bf16, k-contiguous) with x[k0..k0+7]
__device__ __forceinline__ float dot8(const uint4& u, const float* x, int k0) {
  float lo, hi, acc = 0.f;
  bfp(u.x, lo, hi); acc += x[k0  ]*lo + x[k0+1]*hi;
  bfp(u.y, lo, hi); acc += x[k0+2]*lo + x[k0+3]*hi;
  bfp(u.z, lo, hi); acc += x[k0+4]*lo + x[k0+5]*hi;
  bfp(u.w, lo, hi); acc += x[k0+6]*lo + x[k0+7]*hi;
  return acc;
}

// ---------------- weight fp32 -> bf16 (no transposes) ----------------
__global__ void convert_bf16(const float* qkv, const float* ow, const float* f1,
                             const float* f2, const float* w1, unsigned char* ws) {
  __hip_bfloat16* dst = (__hip_bfloat16*)(ws + WB_OFF);
  size_t stride = (size_t)gridDim.x * blockDim.x;
  for (size_t i = (size_t)blockIdx.x * blockDim.x + threadIdx.x; i < NCVT; i += stride) {
    float v;
    if      (i < WOFF_WO)  v = qkv[i];
    else if (i < WOFF_F1)  v = ow[i - WOFF_WO];
    else if (i < WOFF_F2)  v = f1[i - WOFF_F1];
    else if (i < WOFF_OP1) v = f2[i - WOFF_F2];
    else                   v = w1[i - WOFF_OP1];
    dst[i] = __float2bfloat16(v);
  }
}

// ---------------- one-shot per-(g,l): memvec chain + cross-attn const ----------------
// cross-attn K/V rows identical over T -> softmax uniform -> out = V(memvec): constant.
__global__ void precompute_ca(const float* zs, const float* zk,
                              const float* mw1, const float* mb1,
                              const float* mlg, const float* mlb,
                              const float* mw2, const float* mb2,
                              const float* cqw, const float* cqb,
                              const float* cow, const float* cob,
                              unsigned char* ws) {
  const int g = blockIdx.x & 15, l = blockIdx.x >> 4;
  const int tid = threadIdx.x;           // 256 threads
  __shared__ float cond[128], h[256], mvv[256], vv[256], lred[16];

  auto lnstat = [&](float v, float& m, float& rs) {
    float a = v, b = v * v;
    #pragma unroll
    for (int off = 32; off; off >>= 1) { a += __shfl_xor(a, off); b += __shfl_xor(b, off); }
    if ((tid & 63) == 0) { lred[tid >> 6] = a; lred[4 + (tid >> 6)] = b; }
    __syncthreads();
    float sa = lred[0]+lred[1]+lred[2]+lred[3];
    float sb = lred[4]+lred[5]+lred[6]+lred[7];
    m = sa * (1.0f/256.0f);
    rs = rsqrtf(sb * (1.0f/256.0f) - m*m + 1e-5f);
    __syncthreads();
  };

  if (tid < 128) cond[tid] = (tid < 64) ? zs[g*64 + tid] : zk[g*64 + tid - 64];
  __syncthreads();
  float acc = mb1[tid];
  { const float* w = mw1 + (size_t)tid * 128;
    for (int k = 0; k < 128; k += 4) {
      float4 q = *(const float4*)(w + k);
      acc += q.x*cond[k] + q.y*cond[k+1] + q.z*cond[k+2] + q.w*cond[k+3];
    } }
  float m, rs; lnstat(acc, m, rs);
  h[tid] = gelu_exact((acc - m) * rs * mlg[tid] + mlb[tid]);
  __syncthreads();
  float a2 = mb2[tid];
  { const float* w = mw2 + (size_t)tid * 256;
    for (int k = 0; k < 256; k += 4) {
      float4 q = *(const float4*)(w + k);
      a2 += q.x*h[k] + q.y*h[k+1] + q.z*h[k+2] + q.w*h[k+3];
    } }
  mvv[tid] = a2;
  __syncthreads();
  float a3 = cqb[l*768 + 512 + tid];
  { const float* w = cqw + ((size_t)l*768 + 512 + tid) * 256;
    for (int k = 0; k < 256; k += 4) {
      float4 q = *(const float4*)(w + k);
      a3 += q.x*mvv[k] + q.y*mvv[k+1] + q.z*mvv[k+2] + q.w*mvv[k+3];
    } }
  vv[tid] = a3;
  __syncthreads();
  float a4 = cob[l*256 + tid];
  { const float* w = cow + ((size_t)l*256 + tid) * 256;
    for (int k = 0; k < 256; k += 4) {
      float4 q = *(const float4*)(w + k);
      a4 += q.x*vv[k] + q.y*vv[k+1] + q.z*vv[k+2] + q.w*vv[k+3];
    } }
  ((float*)(ws + GRP_OFF))[(size_t)g * GRP_STRF + CAL_F + l*256 + tid] = a4;
}

struct DecP {
  const float *start_token, *emb_w, *emb_b;
  const float *sa_qkv_b, *sa_o_b;
  const float *ln1_g, *ln1_b, *ln2_g, *ln2_b, *ln3_g, *ln3_b;
  const float *ff1_b, *ff2_b;
  const float *op_b1, *op_w2, *op_b2;
  float* out;
  unsigned char* ws;
};

// Persistent decoder: 16 groups x 8 WGs x 512 threads, R3 structure +
// cross-barrier register prefetch of weight tiles + op-head folded into step tail.
__global__ __launch_bounds__(NTHR, 2) void decoder_persistent(DecP p) {
  const int g = blockIdx.x % NGRP;
  const int s = blockIdx.x / NGRP;     // head / ff-slice id 0..7
  const int tid = threadIdx.x;

  unsigned int* cnt = (unsigned int*)(p.ws + CNT_OFF) + (size_t)g * 64;
  float* grp = (float*)(p.ws + GRP_OFF) + (size_t)g * GRP_STRF;
  float* Po = grp + PO_F;
  float* Pf = grp + PF_F;
  const float* CALW = grp + CAL_F;
  const unsigned short* WB = (const unsigned short*)(p.ws + WB_OFF);

  __shared__ float xls[DDIM], x2ls[DDIM], red[NTHR], lred[16], fxl[128];
  __shared__ float qb[HDIM], ah[HDIM], sc[64];
  __shared__ float kc[NLAY*TSEQ*33], vc[NLAY*TSEQ*33];   // padded stride 33
  __shared__ float cals[768], obias[768], ff2b[768];
  __shared__ float ln1g[768], ln1b[768], ln2g[768], ln2b[768], ln3g[768], ln3b[768];
  __shared__ float qkvb[288], ff1b[384];
  __shared__ float embw[DDIM*NOUT], embb[DDIM];
  __shared__ float opb1[128], opw2[NOUT*128], opb2[8], OUTV[8];

  const int olin = tid >> 2, kk = tid & 3;   // A-mapping: 4 threads/output row
  const int oB = tid & 255, khB = tid >> 8;  // B-mapping: 2 threads/output row

  // ---- cross-barrier prefetch buffers (static indexing only) ----
  uint4 pQ[8], pWO[2], pF1[8], pF2[8], pO1[8];
  auto ldQ = [&](int l) {          // own-head qkv: 96 rows x 256, olin<96 active
    if (olin < 96) {
      int sect = olin >> 5, o = olin & 31;
      const unsigned short* w = WB + WOFF_QKV + ((size_t)(l*768 + sect*256 + s*32 + o))*256 + kk*64;
      #pragma unroll
      for (int i = 0; i < 8; ++i) pQ[i] = *(const uint4*)(w + i*8);
    }
  };
  auto ldWO = [&](int l) {         // o-proj rows oB, k in own head (s*32+khB*16..+16)
    const unsigned short* w = WB + WOFF_WO + ((size_t)(l*256 + oB))*256 + s*32 + khB*16;
    pWO[0] = *(const uint4*)(w);
    pWO[1] = *(const uint4*)(w + 8);
  };
  auto ldF1 = [&](int l) {         // ff1 own 128 rows
    const unsigned short* w = WB + WOFF_F1 + ((size_t)(l*1024 + s*128 + olin))*256 + kk*64;
    #pragma unroll
    for (int i = 0; i < 8; ++i) pF1[i] = *(const uint4*)(w + i*8);
  };
  auto ldF2 = [&](int l) {         // ff2 rows oB, k in own 128-slice
    const unsigned short* w = WB + WOFF_F2 + ((size_t)(l*256 + oB))*1024 + s*128 + khB*64;
    #pragma unroll
    for (int i = 0; i < 8; ++i) pF2[i] = *(const uint4*)(w + i*8);
  };
  auto ldO1 = [&]() {              // op_w1 128 rows
    const unsigned short* w = WB + WOFF_OP1 + (size_t)olin*256 + kk*64;
    #pragma unroll
    for (int i = 0; i < 8; ++i) pO1[i] = *(const uint4*)(w + i*8);
  };

  // ---- group barrier (proven R1-R4) ----
  unsigned int barcount = 0;
  auto group_barrier = [&]() {
    __syncthreads();
    ++barcount;
    if (tid == 0) {
      __threadfence();
      __hip_atomic_fetch_add(cnt, 1u, __ATOMIC_RELEASE, __HIP_MEMORY_SCOPE_AGENT);
      unsigned int target = (unsigned int)GWG * barcount;
      while (__hip_atomic_load(cnt, __ATOMIC_RELAXED, __HIP_MEMORY_SCOPE_AGENT) < target)
        __builtin_amdgcn_s_sleep(1);
      (void)__hip_atomic_load(cnt, __ATOMIC_ACQUIRE, __HIP_MEMORY_SCOPE_AGENT);
    }
    __syncthreads();
  };

  auto lnstats = [&](float v, float& m, float& rs) {
    float a = v, b = v * v;
    #pragma unroll
    for (int off = 32; off; off >>= 1) { a += __shfl_xor(a, off); b += __shfl_xor(b, off); }
    if ((tid & 63) == 0) { lred[tid >> 6] = a; lred[8 + (tid >> 6)] = b; }
    __syncthreads();
    float sa = lred[0]+lred[1]+lred[2]+lred[3]+lred[4]+lred[5]+lred[6]+lred[7];
    float sb = lred[8]+lred[9]+lred[10]+lred[11]+lred[12]+lred[13]+lred[14]+lred[15];
    m = sa * (1.0f/256.0f);
    rs = rsqrtf(sb * (1.0f/256.0f) - m*m + 1e-5f);
    __syncthreads();
  };

  // ---- small params -> LDS ----
  for (int i = tid; i < 768; i += NTHR) {
    cals[i]  = CALW[i];
    obias[i] = p.sa_o_b[i];
    ff2b[i]  = p.ff2_b[i];
    ln1g[i] = p.ln1_g[i]; ln1b[i] = p.ln1_b[i];
    ln2g[i] = p.ln2_g[i]; ln2b[i] = p.ln2_b[i];
    ln3g[i] = p.ln3_g[i]; ln3b[i] = p.ln3_b[i];
  }
  for (int i = tid; i < 288; i += NTHR) {
    int l = i / 96, r = i % 96, sect = (r >> 5), o = r & 31;
    qkvb[i] = p.sa_qkv_b[l*768 + sect*256 + s*32 + o];
  }
  for (int i = tid; i < 384; i += NTHR) {
    int l = i >> 7, o = i & 127;
    ff1b[i] = p.ff1_b[l*1024 + s*128 + o];
  }
  for (int i = tid; i < DDIM*NOUT; i += NTHR) embw[i] = p.emb_w[i];
  for (int i = tid; i < DDIM; i += NTHR) embb[i] = p.emb_b[i];
  for (int i = tid; i < 128; i += NTHR) opb1[i] = p.op_b1[i];
  for (int i = tid; i < NOUT*128; i += NTHR) opw2[i] = p.op_w2[i];
  if (tid < NOUT) { opb2[tid] = p.op_b2[tid]; OUTV[tid] = p.start_token[tid]; }

  const float divv = (tid < 256) ? expf(-0.035977892078031968f * (float)(2*(tid>>1))) : 0.f;

  // prologue prefetch for t=0, l=0
  ldQ(0); ldWO(0);
  __syncthreads();

  for (int t = 0; t < TSEQ; ++t) {
    for (int l = 0; l < NLAY; ++l) {
      // ================= PHASE Q: x-build, qkv, attention, oproj partial =========
      if (l == 0) {
        __syncthreads();   // OUTV ready (tail of prev step / prologue)
        if (tid < 256) {
          float ang = (float)t * divv;
          float pe = (tid & 1) ? cosf(ang) : sinf(ang);
          float acc = embb[tid] + pe;
          #pragma unroll
          for (int j = 0; j < NOUT; ++j) acc += OUTV[j] * embw[tid*NOUT + j];
          xls[tid] = acc;
        }
      } else {
        float r2 = 0.f;
        if (tid < 256) {
          r2 = x2ls[tid] + ff2b[(l-1)*256 + tid];
          #pragma unroll
          for (int ss = 0; ss < GWG; ++ss) r2 += Pf[ss*256 + tid];
        }
        float m, rs; lnstats(r2, m, rs);
        if (tid < 256)
          xls[tid] = (r2 - m) * rs * ln3g[(l-1)*256 + tid] + ln3b[(l-1)*256 + tid];
      }
      __syncthreads();
      // qkv GEMV from prefetched regs
      float qacc = 0.f;
      if (olin < 96) {
        #pragma unroll
        for (int i = 0; i < 8; ++i) qacc += dot8(pQ[i], xls, kk*64 + i*8);
      }
      // prefetch this layer's FF tiles (used after B1) -- latency hides under attn
      ldF1(l); ldF2(l);
      if (olin < 96) red[tid] = qacc;
      __syncthreads();
      if (tid < 96) {
        float v = red[tid*4] + red[tid*4+1] + red[tid*4+2] + red[tid*4+3] + qkvb[l*96 + tid];
        int sect = tid >> 5, o = tid & 31;
        if (sect == 0) qb[o] = v;
        else if (sect == 1) kc[(l*TSEQ + t)*33 + o] = v;
        else vc[(l*TSEQ + t)*33 + o] = v;
      }
      __syncthreads();
      // scores + softmax (wave 0)
      if (tid < 64) {
        float scj = -1e30f;
        if (tid <= t) {
          const float* kr = &kc[(l*TSEQ + tid)*33];
          float a = 0.f;
          #pragma unroll
          for (int d = 0; d < HDIM; ++d) a += qb[d] * kr[d];
          scj = a * 0.17677669529663687f;
        }
        float mx = scj;
        #pragma unroll
        for (int off = 32; off; off >>= 1) mx = fmaxf(mx, __shfl_xor(mx, off));
        float e = (tid <= t) ? expf(scj - mx) : 0.f;
        float su = e;
        #pragma unroll
        for (int off = 32; off; off >>= 1) su += __shfl_xor(su, off);
        sc[tid] = e / su;
      }
      __syncthreads();
      // PV: 256 threads, 8 lanes per d
      if (tid < 256) {
        int d = tid >> 3, jg = tid & 7;
        float acc = 0.f;
        for (int j = jg; j <= t; j += 8) acc += sc[j] * vc[(l*TSEQ + j)*33 + d];
        acc += __shfl_xor(acc, 1);
        acc += __shfl_xor(acc, 2);
        acc += __shfl_xor(acc, 4);
        if (jg == 0) ah[d] = acc;
      }
      __syncthreads();
      // oproj partial (own head K-rows)
      {
        float acc = dot8(pWO[0], ah, khB*16) + dot8(pWO[1], ah, khB*16 + 8);
        red[tid] = acc;
      }
      __syncthreads();
      if (tid < 256) Po[s*256 + tid] = red[tid] + red[tid + 256];
      group_barrier();   // B1

      // ================= PHASE F: residual+ln1+ca+ln2, ff1, ff2 partial ==========
      float r = 0.f;
      if (tid < 256) {
        r = xls[tid] + obias[l*256 + tid];
        #pragma unroll
        for (int ss = 0; ss < GWG; ++ss) r += Po[ss*256 + tid];
      }
      float m1, rs1; lnstats(r, m1, rs1);
      float z = 0.f;
      if (tid < 256)
        z = (r - m1)*rs1*ln1g[l*256 + tid] + ln1b[l*256 + tid] + cals[l*256 + tid];
      float m2, rs2; lnstats(z, m2, rs2);
      if (tid < 256) x2ls[tid] = (z - m2)*rs2*ln2g[l*256 + tid] + ln2b[l*256 + tid];
      __syncthreads();
      // ff1 GEMV from prefetched regs
      float facc = 0.f;
      #pragma unroll
      for (int i = 0; i < 8; ++i) facc += dot8(pF1[i], x2ls, kk*64 + i*8);
      // prefetch next phase-Q tiles (next layer, or layer 0 + op1 for the tail)
      {
        int ln = (l == 2) ? 0 : l + 1;
        ldQ(ln); ldWO(ln);
        if (l == 2) ldO1();
      }
      red[tid] = facc;
      __syncthreads();
      if (tid < 128)
        fxl[tid] = gelu_exact(red[tid*4] + red[tid*4+1] + red[tid*4+2] + red[tid*4+3]
                              + ff1b[l*128 + tid]);
      __syncthreads();
      // ff2 partial (own 128 K-slice)
      {
        float acc = 0.f;
        #pragma unroll
        for (int i = 0; i < 8; ++i) acc += dot8(pF2[i], fxl, khB*64 + i*8);
        red[tid] = acc;
      }
      __syncthreads();
      if (tid < 256) Pf[s*256 + tid] = red[tid] + red[tid + 256];
      group_barrier();   // B2
    } // l

    // ============ STEP TAIL: ln3(l2) + output head, redundant on all WGs =========
    {
      float r2 = 0.f;
      if (tid < 256) {
        r2 = x2ls[tid] + ff2b[2*256 + tid];
        #pragma unroll
        for (int ss = 0; ss < GWG; ++ss) r2 += Pf[ss*256 + tid];
      }
      float m, rs; lnstats(r2, m, rs);
      if (tid < 256) xls[tid] = (r2 - m)*rs*ln3g[2*256 + tid] + ln3b[2*256 + tid];
      __syncthreads();
      float oacc = 0.f;
      #pragma unroll
      for (int i = 0; i < 8; ++i) oacc += dot8(pO1[i], xls, kk*64 + i*8);
      red[tid] = oacc;
      __syncthreads();
      if (tid < 128)
        fxl[tid] = gelu_exact(red[tid*4] + red[tid*4+1] + red[tid*4+2] + red[tid*4+3]
                              + opb1[tid]);
      __syncthreads();
      if (tid < 192) {
        int oo = tid >> 5, kl = tid & 31;
        float acc = fxl[kl]*opw2[oo*128 + kl] + fxl[kl+32]*opw2[oo*128 + kl+32]
                  + fxl[kl+64]*opw2[oo*128 + kl+64] + fxl[kl+96]*opw2[oo*128 + kl+96];
        #pragma unroll
        for (int off = 16; off; off >>= 1) acc += __shfl_xor(acc, off);
        if (kl == 0) {
          float v = acc + opb2[oo];
          OUTV[oo] = v;
          if (s == 0) p.out[((size_t)g*TSEQ + t)*NOUT + oo] = v;
        }
      }
      // no barrier: next phase Q(l=0) starts with __syncthreads() before OUTV read
    }
  } // t
}

extern "C" void kernel_launch(void* const* d_in, const int* in_sizes, int n_in,
                              void* d_out, int out_size, void* d_ws, size_t ws_size,
                              hipStream_t stream) {
  const float* const* F = (const float* const*)d_in;
  const float* z_style = F[0]; const float* z_skill = F[1];
  DecP p;
  p.start_token = F[2];
  const float* mem_w1 = F[3]; const float* mem_b1 = F[4];
  const float* mem_ln_g = F[5]; const float* mem_ln_b = F[6];
  const float* mem_w2 = F[7]; const float* mem_b2 = F[8];
  p.emb_w = F[9]; p.emb_b = F[10];
  const float* sa_qkv_w = F[11]; p.sa_qkv_b = F[12];
  const float* sa_o_w  = F[13]; p.sa_o_b = F[14];
  const float* ca_qkv_w = F[15]; const float* ca_qkv_b = F[16];
  const float* ca_o_w = F[17]; const float* ca_o_b = F[18];
  p.ln1_g = F[19]; p.ln1_b = F[20]; p.ln2_g = F[21]; p.ln2_b = F[22];
  p.ln3_g = F[23]; p.ln3_b = F[24];
  const float* ff1_w = F[25]; p.ff1_b = F[26];
  const float* ff2_w = F[27]; p.ff2_b = F[28];
  const float* op_w1 = F[29]; p.op_b1 = F[30]; p.op_w2 = F[31]; p.op_b2 = F[32];
  p.out = (float*)d_out;
  p.ws  = (unsigned char*)d_ws;

  hipMemsetAsync((char*)d_ws + CNT_OFF, 0, CNT_BYTES, stream);
  convert_bf16<<<dim3(512), dim3(256), 0, stream>>>(sa_qkv_w, sa_o_w, ff1_w, ff2_w, op_w1,
                                                    (unsigned char*)d_ws);
  precompute_ca<<<dim3(48), dim3(256), 0, stream>>>(z_style, z_skill, mem_w1, mem_b1,
                                                    mem_ln_g, mem_ln_b, mem_w2, mem_b2,
                                                    ca_qkv_w, ca_qkv_b, ca_o_w, ca_o_b,
                                                    (unsigned char*)d_ws);
  decoder_persistent<<<dim3(NBLK), dim3(NTHR), 0, stream>>>(p);
}

// Round 6
// 2936.657 us; speedup vs baseline: 2.5422x; 1.1724x over previous
//
#include <hip/hip_runtime.h>
#include <hip/hip_bf16.h>
#include <math.h>

// ---------------- problem constants ----------------
#define NGRP 16     // batch groups (one per batch element)
#define GWG  8      // workgroups per group (= heads)
#define NBLK (NGRP*GWG)   // 128
#define NTHR 512
#define TSEQ 48
#define DDIM 256
#define HDIM 32
#define NLAY 3
#define NOUT 6

// ---------------- ws layout ----------------
#define CNT_OFF   0u
#define CNT_BYTES 16384u         // 16 groups x 8 flag slots x 128B
#define GRP_OFF   16384u
#define GRP_STRF  5120u          // floats per group block
#define PO_F   0                 // [8*256] oproj partials
#define PF_F   2048              // [8*256] ff2 partials
#define CAL_F  4096              // [3*256] cross-attn constants
#define WB_OFF 360448u           // bf16 weights (element offsets below)
#define WOFF_QKV 0u
#define WOFF_WO  589824u
#define WOFF_F1  786432u
#define WOFF_F2  1572864u
#define WOFF_OP1 2359296u
#define NCVT     2392064u

__device__ __forceinline__ void bfp(unsigned int u, float& lo, float& hi) {
  union { unsigned int i; float f; } a, b;
  a.i = u << 16; b.i = u & 0xffff0000u; lo = a.f; hi = b.f;
}
__device__ __forceinline__ float gelu_exact(float x) {
  return 0.5f * x * (1.0f + erff(x * 0.70710678118654752f));
}
// dot of one uint4 (8 packed bf16, k-contiguous) with x[k0..k0+7]
__device__ __forceinline__ float dot8(const uint4& u, const float* x, int k0) {
  float lo, hi, acc = 0.f;
  bfp(u.x, lo, hi); acc += x[k0  ]*lo + x[k0+1]*hi;
  bfp(u.y, lo, hi); acc += x[k0+2]*lo + x[k0+3]*hi;
  bfp(u.z, lo, hi); acc += x[k0+4]*lo + x[k0+5]*hi;
  bfp(u.w, lo, hi); acc += x[k0+6]*lo + x[k0+7]*hi;
  return acc;
}

// ---------------- weight fp32 -> bf16 (no transposes) ----------------
__global__ void convert_bf16(const float* qkv, const float* ow, const float* f1,
                             const float* f2, const float* w1, unsigned char* ws) {
  __hip_bfloat16* dst = (__hip_bfloat16*)(ws + WB_OFF);
  size_t stride = (size_t)gridDim.x * blockDim.x;
  for (size_t i = (size_t)blockIdx.x * blockDim.x + threadIdx.x; i < NCVT; i += stride) {
    float v;
    if      (i < WOFF_WO)  v = qkv[i];
    else if (i < WOFF_F1)  v = ow[i - WOFF_WO];
    else if (i < WOFF_F2)  v = f1[i - WOFF_F1];
    else if (i < WOFF_OP1) v = f2[i - WOFF_F2];
    else                   v = w1[i - WOFF_OP1];
    dst[i] = __float2bfloat16(v);
  }
}

// ---------------- one-shot per-(g,l): memvec chain + cross-attn const ----------------
// cross-attn K/V rows identical over T -> softmax uniform -> out = V(memvec): constant.
__global__ void precompute_ca(const float* zs, const float* zk,
                              const float* mw1, const float* mb1,
                              const float* mlg, const float* mlb,
                              const float* mw2, const float* mb2,
                              const float* cqw, const float* cqb,
                              const float* cow, const float* cob,
                              unsigned char* ws) {
  const int g = blockIdx.x & 15, l = blockIdx.x >> 4;
  const int tid = threadIdx.x;           // 256 threads
  __shared__ float cond[128], h[256], mvv[256], vv[256], lred[16];

  auto lnstat = [&](float v, float& m, float& rs) {
    float a = v, b = v * v;
    #pragma unroll
    for (int off = 32; off; off >>= 1) { a += __shfl_xor(a, off); b += __shfl_xor(b, off); }
    if ((tid & 63) == 0) { lred[tid >> 6] = a; lred[4 + (tid >> 6)] = b; }
    __syncthreads();
    float sa = lred[0]+lred[1]+lred[2]+lred[3];
    float sb = lred[4]+lred[5]+lred[6]+lred[7];
    m = sa * (1.0f/256.0f);
    rs = rsqrtf(sb * (1.0f/256.0f) - m*m + 1e-5f);
    __syncthreads();
  };

  if (tid < 128) cond[tid] = (tid < 64) ? zs[g*64 + tid] : zk[g*64 + tid - 64];
  __syncthreads();
  float acc = mb1[tid];
  { const float* w = mw1 + (size_t)tid * 128;
    for (int k = 0; k < 128; k += 4) {
      float4 q = *(const float4*)(w + k);
      acc += q.x*cond[k] + q.y*cond[k+1] + q.z*cond[k+2] + q.w*cond[k+3];
    } }
  float m, rs; lnstat(acc, m, rs);
  h[tid] = gelu_exact((acc - m) * rs * mlg[tid] + mlb[tid]);
  __syncthreads();
  float a2 = mb2[tid];
  { const float* w = mw2 + (size_t)tid * 256;
    for (int k = 0; k < 256; k += 4) {
      float4 q = *(const float4*)(w + k);
      a2 += q.x*h[k] + q.y*h[k+1] + q.z*h[k+2] + q.w*h[k+3];
    } }
  mvv[tid] = a2;
  __syncthreads();
  float a3 = cqb[l*768 + 512 + tid];
  { const float* w = cqw + ((size_t)l*768 + 512 + tid) * 256;
    for (int k = 0; k < 256; k += 4) {
      float4 q = *(const float4*)(w + k);
      a3 += q.x*mvv[k] + q.y*mvv[k+1] + q.z*mvv[k+2] + q.w*mvv[k+3];
    } }
  vv[tid] = a3;
  __syncthreads();
  float a4 = cob[l*256 + tid];
  { const float* w = cow + ((size_t)l*256 + tid) * 256;
    for (int k = 0; k < 256; k += 4) {
      float4 q = *(const float4*)(w + k);
      a4 += q.x*vv[k] + q.y*vv[k+1] + q.z*vv[k+2] + q.w*vv[k+3];
    } }
  ((float*)(ws + GRP_OFF))[(size_t)g * GRP_STRF + CAL_F + l*256 + tid] = a4;
}

struct DecP {
  const float *start_token, *emb_w, *emb_b;
  const float *sa_qkv_b, *sa_o_b;
  const float *ln1_g, *ln1_b, *ln2_g, *ln2_b, *ln3_g, *ln3_b;
  const float *ff1_b, *ff2_b;
  const float *op_b1, *op_w2, *op_b2;
  float* out;
  unsigned char* ws;
};

// Persistent decoder: 16 groups x 8 WGs x 512 threads. R5 body; barrier replaced by
// a flag-vector barrier: arrival = one release STORE per WG (no RMW serialization),
// detection = 8 parallel flag spins in wave 0.
__global__ __launch_bounds__(NTHR, 2) void decoder_persistent(DecP p) {
  const int g = blockIdx.x % NGRP;
  const int s = blockIdx.x / NGRP;     // head / ff-slice id 0..7
  const int tid = threadIdx.x;

  unsigned int* flg = (unsigned int*)(p.ws + CNT_OFF) + (size_t)g * 256;  // 8 slots x 32 uints
  float* grp = (float*)(p.ws + GRP_OFF) + (size_t)g * GRP_STRF;
  float* Po = grp + PO_F;
  float* Pf = grp + PF_F;
  const float* CALW = grp + CAL_F;
  const unsigned short* WB = (const unsigned short*)(p.ws + WB_OFF);

  __shared__ float xls[DDIM], x2ls[DDIM], red[NTHR], lred[16], fxl[128];
  __shared__ float qb[HDIM], ah[HDIM], sc[64];
  __shared__ float kc[NLAY*TSEQ*33], vc[NLAY*TSEQ*33];   // padded stride 33
  __shared__ float cals[768], obias[768], ff2b[768];
  __shared__ float ln1g[768], ln1b[768], ln2g[768], ln2b[768], ln3g[768], ln3b[768];
  __shared__ float qkvb[288], ff1b[384];
  __shared__ float embw[DDIM*NOUT], embb[DDIM];
  __shared__ float opb1[128], opw2[NOUT*128], opb2[8], OUTV[8];

  const int olin = tid >> 2, kk = tid & 3;   // A-mapping: 4 threads/output row
  const int oB = tid & 255, khB = tid >> 8;  // B-mapping: 2 threads/output row

  // ---- cross-barrier prefetch buffers (kept from R5; compiler may sink) ----
  uint4 pQ[8], pWO[2], pF1[8], pF2[8], pO1[8];
  auto ldQ = [&](int l) {          // own-head qkv: 96 rows x 256, olin<96 active
    if (olin < 96) {
      int sect = olin >> 5, o = olin & 31;
      const unsigned short* w = WB + WOFF_QKV + ((size_t)(l*768 + sect*256 + s*32 + o))*256 + kk*64;
      #pragma unroll
      for (int i = 0; i < 8; ++i) pQ[i] = *(const uint4*)(w + i*8);
    }
  };
  auto ldWO = [&](int l) {         // o-proj rows oB, k in own head (s*32+khB*16..+16)
    const unsigned short* w = WB + WOFF_WO + ((size_t)(l*256 + oB))*256 + s*32 + khB*16;
    pWO[0] = *(const uint4*)(w);
    pWO[1] = *(const uint4*)(w + 8);
  };
  auto ldF1 = [&](int l) {         // ff1 own 128 rows
    const unsigned short* w = WB + WOFF_F1 + ((size_t)(l*1024 + s*128 + olin))*256 + kk*64;
    #pragma unroll
    for (int i = 0; i < 8; ++i) pF1[i] = *(const uint4*)(w + i*8);
  };
  auto ldF2 = [&](int l) {         // ff2 rows oB, k in own 128-slice
    const unsigned short* w = WB + WOFF_F2 + ((size_t)(l*256 + oB))*1024 + s*128 + khB*64;
    #pragma unroll
    for (int i = 0; i < 8; ++i) pF2[i] = *(const uint4*)(w + i*8);
  };
  auto ldO1 = [&]() {              // op_w1 128 rows
    const unsigned short* w = WB + WOFF_OP1 + (size_t)olin*256 + kk*64;
    #pragma unroll
    for (int i = 0; i < 8; ++i) pO1[i] = *(const uint4*)(w + i*8);
  };

  // ---- flag-vector group barrier ----
  // arrival: release-store own flag = barcount (no RMW). detection: lanes 0..7 of
  // wave 0 spin one flag each (relaxed), then one acquire load pairs the release
  // and invalidates caches before post-barrier reads (same model as R1-R5).
  unsigned int barcount = 0;
  auto group_barrier = [&]() {
    __syncthreads();   // all waves drain their stores (compiler vmcnt(0) before s_barrier)
    ++barcount;
    if (tid == 0)
      __hip_atomic_store(flg + s*32, barcount, __ATOMIC_RELEASE, __HIP_MEMORY_SCOPE_AGENT);
    if (tid < GWG) {
      while (__hip_atomic_load(flg + tid*32, __ATOMIC_RELAXED, __HIP_MEMORY_SCOPE_AGENT) < barcount) {}
    }
    if (tid == 0)
      (void)__hip_atomic_load(flg + s*32, __ATOMIC_ACQUIRE, __HIP_MEMORY_SCOPE_AGENT);
    __syncthreads();
  };

  auto lnstats = [&](float v, float& m, float& rs) {
    float a = v, b = v * v;
    #pragma unroll
    for (int off = 32; off; off >>= 1) { a += __shfl_xor(a, off); b += __shfl_xor(b, off); }
    if ((tid & 63) == 0) { lred[tid >> 6] = a; lred[8 + (tid >> 6)] = b; }
    __syncthreads();
    float sa = lred[0]+lred[1]+lred[2]+lred[3]+lred[4]+lred[5]+lred[6]+lred[7];
    float sb = lred[8]+lred[9]+lred[10]+lred[11]+lred[12]+lred[13]+lred[14]+lred[15];
    m = sa * (1.0f/256.0f);
    rs = rsqrtf(sb * (1.0f/256.0f) - m*m + 1e-5f);
    __syncthreads();
  };

  // ---- small params -> LDS ----
  for (int i = tid; i < 768; i += NTHR) {
    cals[i]  = CALW[i];
    obias[i] = p.sa_o_b[i];
    ff2b[i]  = p.ff2_b[i];
    ln1g[i] = p.ln1_g[i]; ln1b[i] = p.ln1_b[i];
    ln2g[i] = p.ln2_g[i]; ln2b[i] = p.ln2_b[i];
    ln3g[i] = p.ln3_g[i]; ln3b[i] = p.ln3_b[i];
  }
  for (int i = tid; i < 288; i += NTHR) {
    int l = i / 96, r = i % 96, sect = (r >> 5), o = r & 31;
    qkvb[i] = p.sa_qkv_b[l*768 + sect*256 + s*32 + o];
  }
  for (int i = tid; i < 384; i += NTHR) {
    int l = i >> 7, o = i & 127;
    ff1b[i] = p.ff1_b[l*1024 + s*128 + o];
  }
  for (int i = tid; i < DDIM*NOUT; i += NTHR) embw[i] = p.emb_w[i];
  for (int i = tid; i < DDIM; i += NTHR) embb[i] = p.emb_b[i];
  for (int i = tid; i < 128; i += NTHR) opb1[i] = p.op_b1[i];
  for (int i = tid; i < NOUT*128; i += NTHR) opw2[i] = p.op_w2[i];
  if (tid < NOUT) { opb2[tid] = p.op_b2[tid]; OUTV[tid] = p.start_token[tid]; }

  const float divv = (tid < 256) ? expf(-0.035977892078031968f * (float)(2*(tid>>1))) : 0.f;

  // prologue prefetch for t=0, l=0
  ldQ(0); ldWO(0);
  __syncthreads();

  for (int t = 0; t < TSEQ; ++t) {
    for (int l = 0; l < NLAY; ++l) {
      // ================= PHASE Q: x-build, qkv, attention, oproj partial =========
      if (l == 0) {
        __syncthreads();   // OUTV ready (tail of prev step / prologue)
        if (tid < 256) {
          float ang = (float)t * divv;
          float pe = (tid & 1) ? cosf(ang) : sinf(ang);
          float acc = embb[tid] + pe;
          #pragma unroll
          for (int j = 0; j < NOUT; ++j) acc += OUTV[j] * embw[tid*NOUT + j];
          xls[tid] = acc;
        }
      } else {
        float r2 = 0.f;
        if (tid < 256) {
          r2 = x2ls[tid] + ff2b[(l-1)*256 + tid];
          #pragma unroll
          for (int ss = 0; ss < GWG; ++ss) r2 += Pf[ss*256 + tid];
        }
        float m, rs; lnstats(r2, m, rs);
        if (tid < 256)
          xls[tid] = (r2 - m) * rs * ln3g[(l-1)*256 + tid] + ln3b[(l-1)*256 + tid];
      }
      __syncthreads();
      // qkv GEMV from prefetched regs
      float qacc = 0.f;
      if (olin < 96) {
        #pragma unroll
        for (int i = 0; i < 8; ++i) qacc += dot8(pQ[i], xls, kk*64 + i*8);
      }
      // prefetch this layer's FF tiles (used after B1)
      ldF1(l); ldF2(l);
      if (olin < 96) red[tid] = qacc;
      __syncthreads();
      if (tid < 96) {
        float v = red[tid*4] + red[tid*4+1] + red[tid*4+2] + red[tid*4+3] + qkvb[l*96 + tid];
        int sect = tid >> 5, o = tid & 31;
        if (sect == 0) qb[o] = v;
        else if (sect == 1) kc[(l*TSEQ + t)*33 + o] = v;
        else vc[(l*TSEQ + t)*33 + o] = v;
      }
      __syncthreads();
      // scores + softmax (wave 0)
      if (tid < 64) {
        float scj = -1e30f;
        if (tid <= t) {
          const float* kr = &kc[(l*TSEQ + tid)*33];
          float a = 0.f;
          #pragma unroll
          for (int d = 0; d < HDIM; ++d) a += qb[d] * kr[d];
          scj = a * 0.17677669529663687f;
        }
        float mx = scj;
        #pragma unroll
        for (int off = 32; off; off >>= 1) mx = fmaxf(mx, __shfl_xor(mx, off));
        float e = (tid <= t) ? expf(scj - mx) : 0.f;
        float su = e;
        #pragma unroll
        for (int off = 32; off; off >>= 1) su += __shfl_xor(su, off);
        sc[tid] = e / su;
      }
      __syncthreads();
      // PV: 256 threads, 8 lanes per d
      if (tid < 256) {
        int d = tid >> 3, jg = tid & 7;
        float acc = 0.f;
        for (int j = jg; j <= t; j += 8) acc += sc[j] * vc[(l*TSEQ + j)*33 + d];
        acc += __shfl_xor(acc, 1);
        acc += __shfl_xor(acc, 2);
        acc += __shfl_xor(acc, 4);
        if (jg == 0) ah[d] = acc;
      }
      __syncthreads();
      // oproj partial (own head K-rows)
      {
        float acc = dot8(pWO[0], ah, khB*16) + dot8(pWO[1], ah, khB*16 + 8);
        red[tid] = acc;
      }
      __syncthreads();
      if (tid < 256) Po[s*256 + tid] = red[tid] + red[tid + 256];
      group_barrier();   // B1

      // ================= PHASE F: residual+ln1+ca+ln2, ff1, ff2 partial ==========
      float r = 0.f;
      if (tid < 256) {
        r = xls[tid] + obias[l*256 + tid];
        #pragma unroll
        for (int ss = 0; ss < GWG; ++ss) r += Po[ss*256 + tid];
      }
      float m1, rs1; lnstats(r, m1, rs1);
      float z = 0.f;
      if (tid < 256)
        z = (r - m1)*rs1*ln1g[l*256 + tid] + ln1b[l*256 + tid] + cals[l*256 + tid];
      float m2, rs2; lnstats(z, m2, rs2);
      if (tid < 256) x2ls[tid] = (z - m2)*rs2*ln2g[l*256 + tid] + ln2b[l*256 + tid];
      __syncthreads();
      // ff1 GEMV from prefetched regs
      float facc = 0.f;
      #pragma unroll
      for (int i = 0; i < 8; ++i) facc += dot8(pF1[i], x2ls, kk*64 + i*8);
      // prefetch next phase-Q tiles (next layer, or layer 0 + op1 for the tail)
      {
        int ln = (l == 2) ? 0 : l + 1;
        ldQ(ln); ldWO(ln);
        if (l == 2) ldO1();
      }
      red[tid] = facc;
      __syncthreads();
      if (tid < 128)
        fxl[tid] = gelu_exact(red[tid*4] + red[tid*4+1] + red[tid*4+2] + red[tid*4+3]
                              + ff1b[l*128 + tid]);
      __syncthreads();
      // ff2 partial (own 128 K-slice)
      {
        float acc = 0.f;
        #pragma unroll
        for (int i = 0; i < 8; ++i) acc += dot8(pF2[i], fxl, khB*64 + i*8);
        red[tid] = acc;
      }
      __syncthreads();
      if (tid < 256) Pf[s*256 + tid] = red[tid] + red[tid + 256];
      group_barrier();   // B2
    } // l

    // ============ STEP TAIL: ln3(l2) + output head, redundant on all WGs =========
    {
      float r2 = 0.f;
      if (tid < 256) {
        r2 = x2ls[tid] + ff2b[2*256 + tid];
        #pragma unroll
        for (int ss = 0; ss < GWG; ++ss) r2 += Pf[ss*256 + tid];
      }
      float m, rs; lnstats(r2, m, rs);
      if (tid < 256) xls[tid] = (r2 - m)*rs*ln3g[2*256 + tid] + ln3b[2*256 + tid];
      __syncthreads();
      float oacc = 0.f;
      #pragma unroll
      for (int i = 0; i < 8; ++i) oacc += dot8(pO1[i], xls, kk*64 + i*8);
      red[tid] = oacc;
      __syncthreads();
      if (tid < 128)
        fxl[tid] = gelu_exact(red[tid*4] + red[tid*4+1] + red[tid*4+2] + red[tid*4+3]
                              + opb1[tid]);
      __syncthreads();
      if (tid < 192) {
        int oo = tid >> 5, kl = tid & 31;
        float acc = fxl[kl]*opw2[oo*128 + kl] + fxl[kl+32]*opw2[oo*128 + kl+32]
                  + fxl[kl+64]*opw2[oo*128 + kl+64] + fxl[kl+96]*opw2[oo*128 + kl+96];
        #pragma unroll
        for (int off = 16; off; off >>= 1) acc += __shfl_xor(acc, off);
        if (kl == 0) {
          float v = acc + opb2[oo];
          OUTV[oo] = v;
          if (s == 0) p.out[((size_t)g*TSEQ + t)*NOUT + oo] = v;
        }
      }
      // no barrier: next phase Q(l=0) starts with __syncthreads() before OUTV read
    }
  } // t
}

extern "C" void kernel_launch(void* const* d_in, const int* in_sizes, int n_in,
                              void* d_out, int out_size, void* d_ws, size_t ws_size,
                              hipStream_t stream) {
  const float* const* F = (const float* const*)d_in;
  const float* z_style = F[0]; const float* z_skill = F[1];
  DecP p;
  p.start_token = F[2];
  const float* mem_w1 = F[3]; const float* mem_b1 = F[4];
  const float* mem_ln_g = F[5]; const float* mem_ln_b = F[6];
  const float* mem_w2 = F[7]; const float* mem_b2 = F[8];
  p.emb_w = F[9]; p.emb_b = F[10];
  const float* sa_qkv_w = F[11]; p.sa_qkv_b = F[12];
  const float* sa_o_w  = F[13]; p.sa_o_b = F[14];
  const float* ca_qkv_w = F[15]; const float* ca_qkv_b = F[16];
  const float* ca_o_w = F[17]; const float* ca_o_b = F[18];
  p.ln1_g = F[19]; p.ln1_b = F[20]; p.ln2_g = F[21]; p.ln2_b = F[22];
  p.ln3_g = F[23]; p.ln3_b = F[24];
  const float* ff1_w = F[25]; p.ff1_b = F[26];
  const float* ff2_w = F[27]; p.ff2_b = F[28];
  const float* op_w1 = F[29]; p.op_b1 = F[30]; p.op_w2 = F[31]; p.op_b2 = F[32];
  p.out = (float*)d_out;
  p.ws  = (unsigned char*)d_ws;

  hipMemsetAsync((char*)d_ws + CNT_OFF, 0, CNT_BYTES, stream);
  convert_bf16<<<dim3(512), dim3(256), 0, stream>>>(sa_qkv_w, sa_o_w, ff1_w, ff2_w, op_w1,
                                                    (unsigned char*)d_ws);
  precompute_ca<<<dim3(48), dim3(256), 0, stream>>>(z_style, z_skill, mem_w1, mem_b1,
                                                    mem_ln_g, mem_ln_b, mem_w2, mem_b2,
                                                    ca_qkv_w, ca_qkv_b, ca_o_w, ca_o_b,
                                                    (unsigned char*)d_ws);
  decoder_persistent<<<dim3(NBLK), dim3(NTHR), 0, stream>>>(p);
}

// Round 7
// 2202.268 us; speedup vs baseline: 3.3900x; 1.3335x over previous
//
#include <hip/hip_runtime.h>
#include <hip/hip_bf16.h>
#include <math.h>

// ---------------- problem constants ----------------
#define NGRP 16     // batch groups (one per batch element)
#define GWG  8      // workgroups per group (= heads)
#define NBLK (NGRP*GWG)   // 128
#define NTHR 512
#define TSEQ 48
#define DDIM 256
#define HDIM 32
#define NLAY 3
#define NOUT 6

// ---------------- ws layout ----------------
#define CNT_OFF   0u
#define CNT_BYTES 16384u         // 16 groups x 8 flag slots x 128B
#define GRP_OFF   16384u
#define GRP_STRF  5120u          // floats per group block
#define PO_F   0                 // [8*256] oproj partials
#define PF_F   2048              // [8*256] ff2 partials
#define CAL_F  4096              // [3*256] cross-attn constants
#define WB_OFF 360448u           // bf16 weights (element offsets below)
#define WOFF_QKV 0u
#define WOFF_WO  589824u
#define WOFF_F1  786432u
#define WOFF_F2  1572864u
#define WOFF_OP1 2359296u
#define NCVT     2392064u

typedef __attribute__((address_space(1))) const unsigned int gu32;
typedef __attribute__((address_space(3))) unsigned int lu32;

__device__ __forceinline__ void gl_lds16(const unsigned short* g, unsigned short* l) {
  // async 16B/lane DMA: per-lane global src, wave-uniform LDS base + lane*16
  __builtin_amdgcn_global_load_lds((gu32*)g, (lu32*)l, 16, 0, 0);
}
__device__ __forceinline__ void bfp(unsigned int u, float& lo, float& hi) {
  union { unsigned int i; float f; } a, b;
  a.i = u << 16; b.i = u & 0xffff0000u; lo = a.f; hi = b.f;
}
__device__ __forceinline__ float gelu_exact(float x) {
  return 0.5f * x * (1.0f + erff(x * 0.70710678118654752f));
}
// dot of one uint4 (8 packed bf16, k-contiguous) with x[k0..k0+7]
__device__ __forceinline__ float dot8(const uint4& u, const float* x, int k0) {
  float lo, hi, acc = 0.f;
  bfp(u.x, lo, hi); acc += x[k0  ]*lo + x[k0+1]*hi;
  bfp(u.y, lo, hi); acc += x[k0+2]*lo + x[k0+3]*hi;
  bfp(u.z, lo, hi); acc += x[k0+4]*lo + x[k0+5]*hi;
  bfp(u.w, lo, hi); acc += x[k0+6]*lo + x[k0+7]*hi;
  return acc;
}

// ---------------- weight fp32 -> bf16 (no transposes) ----------------
__global__ void convert_bf16(const float* qkv, const float* ow, const float* f1,
                             const float* f2, const float* w1, unsigned char* ws) {
  __hip_bfloat16* dst = (__hip_bfloat16*)(ws + WB_OFF);
  size_t stride = (size_t)gridDim.x * blockDim.x;
  for (size_t i = (size_t)blockIdx.x * blockDim.x + threadIdx.x; i < NCVT; i += stride) {
    float v;
    if      (i < WOFF_WO)  v = qkv[i];
    else if (i < WOFF_F1)  v = ow[i - WOFF_WO];
    else if (i < WOFF_F2)  v = f1[i - WOFF_F1];
    else if (i < WOFF_OP1) v = f2[i - WOFF_F2];
    else                   v = w1[i - WOFF_OP1];
    dst[i] = __float2bfloat16(v);
  }
}

// ---------------- one-shot per-(g,l): memvec chain + cross-attn const ----------------
// cross-attn K/V rows identical over T -> softmax uniform -> out = V(memvec): constant.
__global__ void precompute_ca(const float* zs, const float* zk,
                              const float* mw1, const float* mb1,
                              const float* mlg, const float* mlb,
                              const float* mw2, const float* mb2,
                              const float* cqw, const float* cqb,
                              const float* cow, const float* cob,
                              unsigned char* ws) {
  const int g = blockIdx.x & 15, l = blockIdx.x >> 4;
  const int tid = threadIdx.x;           // 256 threads
  __shared__ float cond[128], h[256], mvv[256], vv[256], lred[16];

  auto lnstat = [&](float v, float& m, float& rs) {
    float a = v, b = v * v;
    #pragma unroll
    for (int off = 32; off; off >>= 1) { a += __shfl_xor(a, off); b += __shfl_xor(b, off); }
    if ((tid & 63) == 0) { lred[tid >> 6] = a; lred[4 + (tid >> 6)] = b; }
    __syncthreads();
    float sa = lred[0]+lred[1]+lred[2]+lred[3];
    float sb = lred[4]+lred[5]+lred[6]+lred[7];
    m = sa * (1.0f/256.0f);
    rs = rsqrtf(sb * (1.0f/256.0f) - m*m + 1e-5f);
    __syncthreads();
  };

  if (tid < 128) cond[tid] = (tid < 64) ? zs[g*64 + tid] : zk[g*64 + tid - 64];
  __syncthreads();
  float acc = mb1[tid];
  { const float* w = mw1 + (size_t)tid * 128;
    for (int k = 0; k < 128; k += 4) {
      float4 q = *(const float4*)(w + k);
      acc += q.x*cond[k] + q.y*cond[k+1] + q.z*cond[k+2] + q.w*cond[k+3];
    } }
  float m, rs; lnstat(acc, m, rs);
  h[tid] = gelu_exact((acc - m) * rs * mlg[tid] + mlb[tid]);
  __syncthreads();
  float a2 = mb2[tid];
  { const float* w = mw2 + (size_t)tid * 256;
    for (int k = 0; k < 256; k += 4) {
      float4 q = *(const float4*)(w + k);
      a2 += q.x*h[k] + q.y*h[k+1] + q.z*h[k+2] + q.w*h[k+3];
    } }
  mvv[tid] = a2;
  __syncthreads();
  float a3 = cqb[l*768 + 512 + tid];
  { const float* w = cqw + ((size_t)l*768 + 512 + tid) * 256;
    for (int k = 0; k < 256; k += 4) {
      float4 q = *(const float4*)(w + k);
      a3 += q.x*mvv[k] + q.y*mvv[k+1] + q.z*mvv[k+2] + q.w*mvv[k+3];
    } }
  vv[tid] = a3;
  __syncthreads();
  float a4 = cob[l*256 + tid];
  { const float* w = cow + ((size_t)l*256 + tid) * 256;
    for (int k = 0; k < 256; k += 4) {
      float4 q = *(const float4*)(w + k);
      a4 += q.x*vv[k] + q.y*vv[k+1] + q.z*vv[k+2] + q.w*vv[k+3];
    } }
  ((float*)(ws + GRP_OFF))[(size_t)g * GRP_STRF + CAL_F + l*256 + tid] = a4;
}

struct DecP {
  const float *start_token, *emb_w, *emb_b;
  const float *sa_qkv_b, *sa_o_b;
  const float *ln1_g, *ln1_b, *ln2_g, *ln2_b, *ln3_g, *ln3_b;
  const float *ff1_b, *ff2_b;
  const float *op_b1, *op_w2, *op_b2;
  float* out;
  unsigned char* ws;
};

// Persistent decoder: 16 groups x 8 WGs x 512 threads. R6 structure + LDS weight
// staging via global_load_lds (single 64KB region, pipelined one sub-phase ahead,
// XOR-swizzled source gather + swizzled reads) + kk-rotated x reads.
__global__ __launch_bounds__(NTHR, 2) void decoder_persistent(DecP p) {
  const int g = blockIdx.x % NGRP;
  const int s = blockIdx.x / NGRP;     // head / ff-slice id 0..7
  const int tid = threadIdx.x;

  unsigned int* flg = (unsigned int*)(p.ws + CNT_OFF) + (size_t)g * 256;  // 8 slots x 32 uints
  float* grp = (float*)(p.ws + GRP_OFF) + (size_t)g * GRP_STRF;
  float* Po = grp + PO_F;
  float* Pf = grp + PF_F;
  const float* CALW = grp + CAL_F;
  const unsigned short* WB = (const unsigned short*)(p.ws + WB_OFF);

  __shared__ __align__(16) unsigned short Rws[32768];   // 64KB weight stage region
  __shared__ float xls[DDIM], x2ls[DDIM], red[NTHR], lred[16], fxl[128];
  __shared__ float qb[HDIM], ah[HDIM], sc[64];
  __shared__ float kc[NLAY*TSEQ*33], vc[NLAY*TSEQ*33];   // padded stride 33
  __shared__ float cals[768], obias[768], ff2b[768];
  __shared__ float ln1g[768], ln1b[768], ln2g[768], ln2b[768], ln3g[768], ln3b[768];
  __shared__ float qkvb[288], ff1b[384];
  __shared__ float embw[DDIM*NOUT], embb[DDIM];
  __shared__ float opb1[128], opw2[NOUT*128], opb2[8], OUTV[8];

  const int olin = tid >> 2, kk = tid & 3;   // A-mapping: 4 threads/output row
  const int oB = tid & 255, khB = tid >> 8;  // B-mapping: 2 threads/output row
  const int wv = tid >> 6, ln = tid & 63;    // wave id / lane id

  // ---- weight staging (async DMA; swizzled source gather, linear LDS dest) ----
  // swizzle: LDS[row*RS + cb] = G[row, cb ^ ((row&7)<<4)]; read applies same XOR.
  auto stage_qkv = [&](int l) {     // 96 rows x 512B (3072 chunks, 6 rounds)
    #pragma unroll
    for (int r = 0; r < 6; ++r) {
      int c = (r*8 + wv)*64 + ln;
      int row = c >> 5, wc = (c & 31) ^ (row & 7);
      const unsigned short* gp = WB + WOFF_QKV
        + ((size_t)(l*768 + (row>>5)*256 + s*32 + (row&31)))*256 + wc*8;
      gl_lds16(gp, Rws + (size_t)(r*8 + wv)*512);
    }
  };
  auto stage_ff1 = [&](int l) {     // 128 rows x 512B (4096 chunks, 8 rounds)
    #pragma unroll
    for (int r = 0; r < 8; ++r) {
      int c = (r*8 + wv)*64 + ln;
      int row = c >> 5, wc = (c & 31) ^ (row & 7);
      const unsigned short* gp = WB + WOFF_F1
        + ((size_t)(l*1024 + s*128 + row))*256 + wc*8;
      gl_lds16(gp, Rws + (size_t)(r*8 + wv)*512);
    }
  };
  auto stage_ff2 = [&](int l) {     // 256 rows x 256B (4096 chunks, 8 rounds)
    #pragma unroll
    for (int r = 0; r < 8; ++r) {
      int c = (r*8 + wv)*64 + ln;
      int row = c >> 4, wc = (c & 15) ^ (row & 7);
      const unsigned short* gp = WB + WOFF_F2
        + ((size_t)(l*256 + row))*1024 + s*128 + wc*8;
      gl_lds16(gp, Rws + (size_t)(r*8 + wv)*512);
    }
  };

  // ---- small direct register loads (tiny tiles) ----
  uint4 pWO[2], pO1[8];
  auto ldWO = [&](int l) {         // o-proj rows oB, k in own head
    const unsigned short* w = WB + WOFF_WO + ((size_t)(l*256 + oB))*256 + s*32 + khB*16;
    pWO[0] = *(const uint4*)(w);
    pWO[1] = *(const uint4*)(w + 8);
  };
  auto ldO1 = [&]() {              // op_w1 128 rows
    const unsigned short* w = WB + WOFF_OP1 + (size_t)olin*256 + kk*64;
    #pragma unroll
    for (int i = 0; i < 8; ++i) pO1[i] = *(const uint4*)(w + i*8);
  };

  // ---- flag-vector group barrier (R6-proven) ----
  unsigned int barcount = 0;
  auto group_barrier = [&]() {
    __syncthreads();
    ++barcount;
    if (tid == 0)
      __hip_atomic_store(flg + s*32, barcount, __ATOMIC_RELEASE, __HIP_MEMORY_SCOPE_AGENT);
    if (tid < GWG) {
      while (__hip_atomic_load(flg + tid*32, __ATOMIC_RELAXED, __HIP_MEMORY_SCOPE_AGENT) < barcount) {}
    }
    if (tid == 0)
      (void)__hip_atomic_load(flg + s*32, __ATOMIC_ACQUIRE, __HIP_MEMORY_SCOPE_AGENT);
    __syncthreads();
  };

  auto lnstats = [&](float v, float& m, float& rs) {
    float a = v, b = v * v;
    #pragma unroll
    for (int off = 32; off; off >>= 1) { a += __shfl_xor(a, off); b += __shfl_xor(b, off); }
    if ((tid & 63) == 0) { lred[tid >> 6] = a; lred[8 + (tid >> 6)] = b; }
    __syncthreads();
    float sa = lred[0]+lred[1]+lred[2]+lred[3]+lred[4]+lred[5]+lred[6]+lred[7];
    float sb = lred[8]+lred[9]+lred[10]+lred[11]+lred[12]+lred[13]+lred[14]+lred[15];
    m = sa * (1.0f/256.0f);
    rs = rsqrtf(sb * (1.0f/256.0f) - m*m + 1e-5f);
    __syncthreads();
  };

  // ---- small params -> LDS ----
  for (int i = tid; i < 768; i += NTHR) {
    cals[i]  = CALW[i];
    obias[i] = p.sa_o_b[i];
    ff2b[i]  = p.ff2_b[i];
    ln1g[i] = p.ln1_g[i]; ln1b[i] = p.ln1_b[i];
    ln2g[i] = p.ln2_g[i]; ln2b[i] = p.ln2_b[i];
    ln3g[i] = p.ln3_g[i]; ln3b[i] = p.ln3_b[i];
  }
  for (int i = tid; i < 288; i += NTHR) {
    int l = i / 96, r = i % 96, sect = (r >> 5), o = r & 31;
    qkvb[i] = p.sa_qkv_b[l*768 + sect*256 + s*32 + o];
  }
  for (int i = tid; i < 384; i += NTHR) {
    int l = i >> 7, o = i & 127;
    ff1b[i] = p.ff1_b[l*1024 + s*128 + o];
  }
  for (int i = tid; i < DDIM*NOUT; i += NTHR) embw[i] = p.emb_w[i];
  for (int i = tid; i < DDIM; i += NTHR) embb[i] = p.emb_b[i];
  for (int i = tid; i < 128; i += NTHR) opb1[i] = p.op_b1[i];
  for (int i = tid; i < NOUT*128; i += NTHR) opw2[i] = p.op_w2[i];
  if (tid < NOUT) { opb2[tid] = p.op_b2[tid]; OUTV[tid] = p.start_token[tid]; }

  const float divv = (tid < 256) ? expf(-0.035977892078031968f * (float)(2*(tid>>1))) : 0.f;

  // prologue: stage QKV(0); direct-load WO(0)
  stage_qkv(0);
  ldWO(0);
  __syncthreads();   // drains DMA (vmcnt 0) + param stores

  for (int t = 0; t < TSEQ; ++t) {
    for (int l = 0; l < NLAY; ++l) {
      // ================= PHASE Q: x-build, qkv (LDS wts), attn, oproj partial =====
      if (l == 0) {
        __syncthreads();   // OUTV ready (tail of prev step / prologue)
        if (tid < 256) {
          float ang = (float)t * divv;
          float pe = (tid & 1) ? cosf(ang) : sinf(ang);
          float acc = embb[tid] + pe;
          #pragma unroll
          for (int j = 0; j < NOUT; ++j) acc += OUTV[j] * embw[tid*NOUT + j];
          xls[tid] = acc;
        }
      } else {
        float r2 = 0.f;
        if (tid < 256) {
          r2 = x2ls[tid] + ff2b[(l-1)*256 + tid];
          #pragma unroll
          for (int ss = 0; ss < GWG; ++ss) r2 += Pf[ss*256 + tid];
        }
        float m, rs; lnstats(r2, m, rs);
        if (tid < 256)
          xls[tid] = (r2 - m) * rs * ln3g[(l-1)*256 + tid] + ln3b[(l-1)*256 + tid];
      }
      __syncthreads();
      // qkv GEMV from staged LDS weights (swizzled read, kk-rotated k-order)
      if (olin < 96) {
        float acc = 0.f;
        #pragma unroll
        for (int i = 0; i < 8; ++i) {
          int ii = (i + kk) & 7;
          int k0 = kk*64 + ii*8;
          const uint4 w = *(const uint4*)(Rws + olin*256 + (k0 ^ ((olin&7)<<3)));
          acc += dot8(w, xls, k0);
        }
        red[tid] = acc;
      }
      __syncthreads();           // all R reads done -> region free
      stage_ff1(l);              // async: completes by the next sync's vmcnt drain
      if (tid < 96) {
        float v = red[tid*4] + red[tid*4+1] + red[tid*4+2] + red[tid*4+3] + qkvb[l*96 + tid];
        int sect = tid >> 5, o = tid & 31;
        if (sect == 0) qb[o] = v;
        else if (sect == 1) kc[(l*TSEQ + t)*33 + o] = v;
        else vc[(l*TSEQ + t)*33 + o] = v;
      }
      __syncthreads();
      // scores + softmax (wave 0)
      if (tid < 64) {
        float scj = -1e30f;
        if (tid <= t) {
          const float* kr = &kc[(l*TSEQ + tid)*33];
          float a = 0.f;
          #pragma unroll
          for (int d = 0; d < HDIM; ++d) a += qb[d] * kr[d];
          scj = a * 0.17677669529663687f;
        }
        float mx = scj;
        #pragma unroll
        for (int off = 32; off; off >>= 1) mx = fmaxf(mx, __shfl_xor(mx, off));
        float e = (tid <= t) ? expf(scj - mx) : 0.f;
        float su = e;
        #pragma unroll
        for (int off = 32; off; off >>= 1) su += __shfl_xor(su, off);
        sc[tid] = e / su;
      }
      __syncthreads();
      // PV: 256 threads, 8 lanes per d
      if (tid < 256) {
        int d = tid >> 3, jg = tid & 7;
        float acc = 0.f;
        for (int j = jg; j <= t; j += 8) acc += sc[j] * vc[(l*TSEQ + j)*33 + d];
        acc += __shfl_xor(acc, 1);
        acc += __shfl_xor(acc, 2);
        acc += __shfl_xor(acc, 4);
        if (jg == 0) ah[d] = acc;
      }
      __syncthreads();
      // oproj partial (own head K-rows, register tile)
      red[tid] = dot8(pWO[0], ah, khB*16) + dot8(pWO[1], ah, khB*16 + 8);
      __syncthreads();
      if (tid < 256) Po[s*256 + tid] = red[tid] + red[tid + 256];
      group_barrier();   // B1 (ff1 DMA drained here at latest)

      // ================= PHASE F: residual+ln1+ca+ln2, ff1, ff2 partial ==========
      float r = 0.f;
      if (tid < 256) {
        r = xls[tid] + obias[l*256 + tid];
        #pragma unroll
        for (int ss = 0; ss < GWG; ++ss) r += Po[ss*256 + tid];
      }
      float m1, rs1; lnstats(r, m1, rs1);
      float z = 0.f;
      if (tid < 256)
        z = (r - m1)*rs1*ln1g[l*256 + tid] + ln1b[l*256 + tid] + cals[l*256 + tid];
      float m2, rs2; lnstats(z, m2, rs2);
      if (tid < 256) x2ls[tid] = (z - m2)*rs2*ln2g[l*256 + tid] + ln2b[l*256 + tid];
      __syncthreads();
      // ff1 GEMV from staged LDS (own 128 rows; o1 = tid>>2 = olin<128 always)
      {
        float acc = 0.f;
        #pragma unroll
        for (int i = 0; i < 8; ++i) {
          int ii = (i + kk) & 7;
          int k0 = kk*64 + ii*8;
          const uint4 w = *(const uint4*)(Rws + olin*256 + (k0 ^ ((olin&7)<<3)));
          acc += dot8(w, x2ls, k0);
        }
        red[tid] = acc;
      }
      __syncthreads();           // R reads done
      stage_ff2(l);              // async; drained by the post-gelu sync
      if (tid < 128)
        fxl[tid] = gelu_exact(red[tid*4] + red[tid*4+1] + red[tid*4+2] + red[tid*4+3]
                              + ff1b[l*128 + tid]);
      __syncthreads();
      // ff2 partial: thread (oB,khB) -> row oB, own 64-elem k-half
      {
        float acc = 0.f;
        #pragma unroll
        for (int j = 0; j < 8; ++j) {
          int k0 = khB*64 + j*8;
          const uint4 w = *(const uint4*)(Rws + oB*128 + (k0 ^ ((oB&7)<<3)));
          acc += dot8(w, fxl, k0);
        }
        red[tid] = acc;
      }
      __syncthreads();           // R reads done
      {
        int lnx = (l == 2) ? 0 : l + 1;
        stage_qkv(lnx);          // async; drained across B2
        ldWO(lnx);
        if (l == 2) ldO1();
      }
      if (tid < 256) Pf[s*256 + tid] = red[tid] + red[tid + 256];
      group_barrier();   // B2
    } // l

    // ============ STEP TAIL: ln3(l2) + output head, redundant on all WGs =========
    {
      float r2 = 0.f;
      if (tid < 256) {
        r2 = x2ls[tid] + ff2b[2*256 + tid];
        #pragma unroll
        for (int ss = 0; ss < GWG; ++ss) r2 += Pf[ss*256 + tid];
      }
      float m, rs; lnstats(r2, m, rs);
      if (tid < 256) xls[tid] = (r2 - m)*rs*ln3g[2*256 + tid] + ln3b[2*256 + tid];
      __syncthreads();
      float oacc = 0.f;
      #pragma unroll
      for (int i = 0; i < 8; ++i) oacc += dot8(pO1[i], xls, kk*64 + i*8);
      red[tid] = oacc;
      __syncthreads();
      if (tid < 128)
        fxl[tid] = gelu_exact(red[tid*4] + red[tid*4+1] + red[tid*4+2] + red[tid*4+3]
                              + opb1[tid]);
      __syncthreads();
      if (tid < 192) {
        int oo = tid >> 5, kl = tid & 31;
        float acc = fxl[kl]*opw2[oo*128 + kl] + fxl[kl+32]*opw2[oo*128 + kl+32]
                  + fxl[kl+64]*opw2[oo*128 + kl+64] + fxl[kl+96]*opw2[oo*128 + kl+96];
        #pragma unroll
        for (int off = 16; off; off >>= 1) acc += __shfl_xor(acc, off);
        if (kl == 0) {
          float v = acc + opb2[oo];
          OUTV[oo] = v;
          if (s == 0) p.out[((size_t)g*TSEQ + t)*NOUT + oo] = v;
        }
      }
      // no barrier: next phase Q(l=0) starts with __syncthreads() before OUTV read
    }
  } // t
}

extern "C" void kernel_launch(void* const* d_in, const int* in_sizes, int n_in,
                              void* d_out, int out_size, void* d_ws, size_t ws_size,
                              hipStream_t stream) {
  const float* const* F = (const float* const*)d_in;
  const float* z_style = F[0]; const float* z_skill = F[1];
  DecP p;
  p.start_token = F[2];
  const float* mem_w1 = F[3]; const float* mem_b1 = F[4];
  const float* mem_ln_g = F[5]; const float* mem_ln_b = F[6];
  const float* mem_w2 = F[7]; const float* mem_b2 = F[8];
  p.emb_w = F[9]; p.emb_b = F[10];
  const float* sa_qkv_w = F[11]; p.sa_qkv_b = F[12];
  const float* sa_o_w  = F[13]; p.sa_o_b = F[14];
  const float* ca_qkv_w = F[15]; const float* ca_qkv_b = F[16];
  const float* ca_o_w = F[17]; const float* ca_o_b = F[18];
  p.ln1_g = F[19]; p.ln1_b = F[20]; p.ln2_g = F[21]; p.ln2_b = F[22];
  p.ln3_g = F[23]; p.ln3_b = F[24];
  const float* ff1_w = F[25]; p.ff1_b = F[26];
  const float* ff2_w = F[27]; p.ff2_b = F[28];
  const float* op_w1 = F[29]; p.op_b1 = F[30]; p.op_w2 = F[31]; p.op_b2 = F[32];
  p.out = (float*)d_out;
  p.ws  = (unsigned char*)d_ws;

  hipMemsetAsync((char*)d_ws + CNT_OFF, 0, CNT_BYTES, stream);
  convert_bf16<<<dim3(512), dim3(256), 0, stream>>>(sa_qkv_w, sa_o_w, ff1_w, ff2_w, op_w1,
                                                    (unsigned char*)d_ws);
  precompute_ca<<<dim3(48), dim3(256), 0, stream>>>(z_style, z_skill, mem_w1, mem_b1,
                                                    mem_ln_g, mem_ln_b, mem_w2, mem_b2,
                                                    ca_qkv_w, ca_qkv_b, ca_o_w, ca_o_b,
                                                    (unsigned char*)d_ws);
  decoder_persistent<<<dim3(NBLK), dim3(NTHR), 0, stream>>>(p);
}